// Round 2
// baseline (522.768 us; speedup 1.0000x reference)
//
#include <hip/hip_runtime.h>
#include <float.h>

// VQ-VAE vector quantizer, MI355X fp32 vector-ALU version, round 5.
// z: [32,64,32,32] f32, codebook: [1024,64] f32
// out (f32 flat): z_q [2097152] | loss [1] | indices-as-float [32768]
//
// Numerics contract (DO NOT CHANGE — bitwise-matches the numpy fp32 ref):
//  - code/pixel norms: numpy pairwise-sum tree over 64 rounded squares,
//    fp contract OFF (streamed in 8-element chunks, identical order/grouping)
//  - dot: single c-ascending fma chain per (pixel, code)
//  - score: fl(fl(zz+ee) - 2*dot), strict-< first-min, ascending k,
//    wave w owns codes [w*128, w*128+128)
//
// Round-5 perf change: round 4's launch_bounds(512,4) made the allocator
// SPILL vz[64] to scratch (WRITE_SIZE 8.3->14.5 MB proved it). vz now lives
// in LDS (16 KB/block, XOR-swizzled vs the 32-way bank conflict of
// row-stride-256B ds_read_b128), read once per 8-code step so each 16 B
// LDS read feeds 32 fmas (LDS pipe <= 25% of peak). Per-lane register
// state is ~40 regs by construction -> 16 waves/CU without spill.

#define DIM       64
#define N_EMB     1024
#define LOSS_OFF  2097152
#define IDX_OFF   2097153
// loss = 1.25 * sum / 2^21  (exact fp32 constant)
#define LOSS_SCALE 5.9604644775390625e-07f

// grid 512 blocks x 512 threads; block = 64 pixels (1/lane),
// 8 waves x 128-code slices
__global__ __launch_bounds__(512, 4)
void vq_main(const float* __restrict__ z, const float* __restrict__ cb,
             float* __restrict__ out, float* __restrict__ ws_partial) {
    __shared__ float  esq[N_EMB];          // 4 KB
    __shared__ float4 vzl4[64 * 16];       // 16 KB, swizzled pixel vectors
    __shared__ float  zzs[64];
    __shared__ float  cand_val[8 * 64];
    __shared__ int    cand_idx[8 * 64];
    __shared__ int    fidx[64];
    __shared__ float  lred[8];
    float* vzl = (float*)vzl4;

    const int tid  = threadIdx.x;
    const int lane = tid & 63;
    const int wave = __builtin_amdgcn_readfirstlane(tid >> 6);  // uniform
    const int n0   = blockIdx.x * 64;          // first pixel of this block
    const int b    = n0 >> 10;                 // batch image (1024 px each)
    const int hw0  = n0 & 1023;
    const size_t zbase = (size_t)b * 65536 + (size_t)hw0;  // z[b][c][hw]

    // ---- 1) codebook squared norms -> LDS (2 codes/thread) ----
    // Streamed 8-at-a-time; element order & pairwise tree identical to
    // np_sumsq64: r[j] = sum_m (a[j+8m]^2) ascending m, then pairwise.
    {
        #pragma clang fp contract(off)
        for (int t = 0; t < 2; ++t) {
            const int k = tid * 2 + t;
            const float4* row = (const float4*)(cb + (size_t)k * DIM);
            float r[8];
            #pragma unroll
            for (int m = 0; m < 8; ++m) {
                const float4 x0 = row[2 * m];
                const float4 x1 = row[2 * m + 1];
                const float a[8] = {x0.x, x0.y, x0.z, x0.w,
                                    x1.x, x1.y, x1.z, x1.w};
                #pragma unroll
                for (int j = 0; j < 8; ++j) {
                    const float p = a[j] * a[j];
                    if (m == 0) r[j] = p; else r[j] = r[j] + p;
                }
            }
            esq[k] = ((r[0] + r[1]) + (r[2] + r[3]))
                   + ((r[4] + r[5]) + (r[6] + r[7]));
        }
    }

    // ---- 2) wave 0: stage 64 pixel vectors -> LDS (swizzled) + zz ----
    if (wave == 0) {
        #pragma clang fp contract(off)
        const int sw = (lane & 7) << 2;        // 16B-slot XOR swizzle
        float r[8];
        #pragma unroll
        for (int m = 0; m < 8; ++m) {
            float a[8];
            #pragma unroll
            for (int j = 0; j < 8; ++j)
                a[j] = z[zbase + (size_t)(8 * m + j) * 1024 + lane]; // coalesced
            #pragma unroll
            for (int j = 0; j < 8; ++j) {
                const float p = a[j] * a[j];
                if (m == 0) r[j] = p; else r[j] = r[j] + p;
            }
            const int w0 = lane * DIM + ((8 * m)     ^ sw);
            const int w1 = lane * DIM + ((8 * m + 4) ^ sw);
            *(float4*)&vzl[w0] = make_float4(a[0], a[1], a[2], a[3]);
            *(float4*)&vzl[w1] = make_float4(a[4], a[5], a[6], a[7]);
        }
        zzs[lane] = ((r[0] + r[1]) + (r[2] + r[3]))
                  + ((r[4] + r[5]) + (r[6] + r[7]));
    }
    __syncthreads();

    // ---- 3) argmin over this wave's 128-code slice, 8 codes/step ----
    // Each ds_read_b128 of vz feeds 32 fmas -> LDS pipe ~25% of peak.
    const float zz = zzs[lane];
    const int   sw = (lane & 7) << 2;
    float best = FLT_MAX;
    int   bidx = 0;
    const int kbase = wave * 128;
    for (int k = kbase; k < kbase + 128; k += 8) {   // uniform k -> s_load rows
        const float* e = cb + (size_t)k * DIM;
        float d[8] = {0.f, 0.f, 0.f, 0.f, 0.f, 0.f, 0.f, 0.f};
        #pragma unroll
        for (int t = 0; t < 16; ++t) {
            const float4 v = *(const float4*)&vzl[lane * DIM + ((4 * t) ^ sw)];
            const float va[4] = {v.x, v.y, v.z, v.w};
            #pragma unroll
            for (int j = 0; j < 4; ++j) {
                const int c = 4 * t + j;             // ascending c per chain
                #pragma unroll
                for (int q = 0; q < 8; ++q)
                    d[q] = __builtin_fmaf(e[q * DIM + c], va[j], d[q]);
            }
        }
        {
            #pragma clang fp contract(off)
            #pragma unroll
            for (int q = 0; q < 8; ++q) {            // ascending k =>
                const float p = zz + esq[k + q];     // first-min kept
                const float s = p - 2.0f * d[q];
                if (s < best) { best = s; bidx = k + q; }
            }
        }
    }
    cand_val[wave * 64 + lane] = best;
    cand_idx[wave * 64 + lane] = bidx;
    __syncthreads();

    // ---- 4) reduce 8 wave-candidates per pixel; write indices output ----
    if (tid < 64) {
        float bv = cand_val[tid];
        int   bi = cand_idx[tid];
        #pragma unroll
        for (int w = 1; w < 8; ++w) {
            float v = cand_val[w * 64 + tid];
            int   i = cand_idx[w * 64 + tid];
            if (v < bv || (v == bv && i < bi)) { bv = v; bi = i; }
        }
        fidx[tid] = bi;
        out[IDX_OFF + n0 + tid] = (float)bi;
    }
    __syncthreads();

    // ---- 5) z_q write (coalesced by hw) + loss partial ----
    // 512 threads: px = lane, wave cg handles channels cg*8 .. cg*8+7
    const int px = tid & 63;
    const int cg = tid >> 6;      // 0..7
    const int mi = fidx[px];
    float lacc = 0.f;
    #pragma unroll
    for (int i = 0; i < 8; ++i) {
        const int c = cg * 8 + i;
        float q  = cb[mi * DIM + c];                        // L2-resident gather
        float zv = vzl[px * DIM + (c ^ ((px & 7) << 2))];   // bitwise == z load
        size_t go = zbase + (size_t)c * 1024 + px;
        float dd = q - zv;
        lacc = __builtin_fmaf(dd, dd, lacc);
        out[go] = q;                                        // coalesced
    }
    #pragma unroll
    for (int off = 32; off > 0; off >>= 1)
        lacc += __shfl_down(lacc, off, 64);
    if (lane == 0) lred[wave] = lacc;
    __syncthreads();
    if (tid == 0) {
        float t = 0.f;
        #pragma unroll
        for (int w = 0; w < 8; ++w) t += lred[w];
        ws_partial[blockIdx.x] = t;
    }
}

// single block, 512 threads: sum the 512 block partials -> loss
__global__ __launch_bounds__(512)
void vq_loss_finalize(const float* __restrict__ ws_partial, float* __restrict__ out) {
    __shared__ float red[8];
    const int tid = threadIdx.x;
    float v = ws_partial[tid];
    #pragma unroll
    for (int off = 32; off > 0; off >>= 1)
        v += __shfl_down(v, off, 64);
    const int lane = tid & 63, wave = tid >> 6;
    if (lane == 0) red[wave] = v;
    __syncthreads();
    if (tid == 0) {
        float t = 0.f;
        #pragma unroll
        for (int w = 0; w < 8; ++w) t += red[w];
        out[LOSS_OFF] = t * LOSS_SCALE;
    }
}

extern "C" void kernel_launch(void* const* d_in, const int* in_sizes, int n_in,
                              void* d_out, int out_size, void* d_ws, size_t ws_size,
                              hipStream_t stream) {
    const float* z  = (const float*)d_in[0];   // 2097152 f32
    const float* cb = (const float*)d_in[1];   // 65536 f32
    float* out = (float*)d_out;
    float* ws  = (float*)d_ws;                 // needs 512 * 4 B

    vq_main<<<512, 512, 0, stream>>>(z, cb, out, ws);
    vq_loss_finalize<<<1, 512, 0, stream>>>(ws, out);
}